// Round 6
// baseline (84.740 us; speedup 1.0000x reference)
//
#include <hip/hip_runtime.h>

// CTC batch cost, B=64 T=1024 C=512 (blank=C-1) L=128, S=2L+1=257.
// q-ratio probability-domain forward scan:
//   alpha-hat divides out the blank emission each step: blank states are
//   pure adds, label states multiply by q = (y_lab+eps)/(y_blank+eps).
//   alpha_true = alpha_hat * 2^ksum * prod_t eb(t),
//   loss = -(log(p255+p256) + ksum*ln2 + sum_t log eb(t)).
// Lane l owns states 4l..4l+3; state 256 lives only in lane 63 (pS).
// Neighbor exchange via DPP wave_shr:1 (0x138); rescale every 16 steps.
// Scan structure: single-buffer CHUNK=64 [load][fence][process][fence] so
// the vmcnt drain amortizes over 64 steps (compiler drains vmcnt(0) right
// after the newest issue otherwise — rounds 3-5 evidence). 512-thread
// blocks (8 independent batch-waves) give 2 waves/SIMD to hide stalls.

#define EPSF 1e-7f
static constexpr int NB = 64;
static constexpr int NT = 1024;
static constexpr int NC = 512;
static constexpr int NL = 128;
static constexpr int CHUNK = 64;
static constexpr int NCH = NT / CHUNK;  // 16

typedef unsigned int uint32;

__device__ __forceinline__ unsigned short rn_bf16(float x) {
    uint32 b = __float_as_uint(x);
    return (unsigned short)((b + 0x7FFFu + ((b >> 16) & 1u)) >> 16);
}

// ---------------- kernel A: rowsum + q-gather, bf16-packed ----------------
__global__ __launch_bounds__(256) void ctc_prep(const float* __restrict__ Y,
                                                const int* __restrict__ y_true,
                                                uint32* __restrict__ qlab,
                                                float* __restrict__ eblank,
                                                int mode) {
    int gtid = blockIdx.x * 256 + threadIdx.x;
    int w = gtid >> 6;           // 0..B*T-1  (b*NT + t)
    int lane = gtid & 63;
    int b = w >> 10;
    const float* row = Y + (size_t)w * NC;

    float4 v0 = *reinterpret_cast<const float4*>(row + lane * 4);
    float4 v1 = *reinterpret_cast<const float4*>(row + (NC / 2) + lane * 4);
    float s = ((v0.x + v0.y) + (v0.z + v0.w)) + ((v1.x + v1.y) + (v1.z + v1.w));
#pragma unroll
    for (int d = 1; d < 64; d <<= 1) s += __shfl_xor(s, d);

    if (mode == 1) {
        float rb = row[NC - 1] + EPSF;        // wave-uniform
        float inv = 1.0f / (s + NC * EPSF);
        float rbi = 1.0f / rb;
        int2 lp = *reinterpret_cast<const int2*>(y_true + b * NL + lane * 2);
        float qx = (row[lp.x] + EPSF) * rbi;
        float qy = (row[lp.y] + EPSF) * rbi;
        uint32 pk = (uint32)rn_bf16(qx) | ((uint32)rn_bf16(qy) << 16);
        qlab[(size_t)w * (NL / 2) + lane] = pk;
        if (lane == 0) eblank[w] = rb * inv;  // true normalized blank prob
    } else {
        if (lane == 0) eblank[w] = 256.0f / (s + NC * EPSF);  // legacy fallback
    }
}

// ---------------- DPP helpers ----------------
__device__ __forceinline__ float dpp_wave_shr1(float x) {
    // lane l <- lane l-1, lane 0 <- 0   (DPP_CTRL 0x138 = WAVE_SHR1)
    return __int_as_float(__builtin_amdgcn_update_dpp(
        0, __float_as_int(x), 0x138, 0xF, 0xF, true));
}

__device__ __forceinline__ float dpp_wave_max(float m) {
#define DPPMAX_(ctrl)                                                     \
    m = fmaxf(m, __int_as_float(__builtin_amdgcn_update_dpp(              \
                     0, __float_as_int(m), ctrl, 0xF, 0xF, true)))
    DPPMAX_(0x111); DPPMAX_(0x112); DPPMAX_(0x114); DPPMAX_(0x118);
    DPPMAX_(0x142); DPPMAX_(0x143);
#undef DPPMAX_
    return __int_as_float(
        __builtin_amdgcn_readlane(__float_as_int(m), 63));
}

// add-reduce: lane 63 ends with the full wave sum
__device__ __forceinline__ float dpp_wave_sum63(float v) {
#define DPPADD_(ctrl)                                                     \
    v += __int_as_float(__builtin_amdgcn_update_dpp(                      \
        0, __float_as_int(v), ctrl, 0xF, 0xF, true))
    DPPADD_(0x111); DPPADD_(0x112); DPPADD_(0x114); DPPADD_(0x118);
    DPPADD_(0x142); DPPADD_(0x143);
#undef DPPADD_
    return v;
}

// ---------------- kernel B: the scan (q-form, 8 waves/block) -------------
__global__ __launch_bounds__(512) void ctc_rec1(const uint32* __restrict__ A,
                                                const float* __restrict__ Bv,
                                                const int* __restrict__ y_true,
                                                float* __restrict__ out) {
    const int wid = threadIdx.x >> 6;
    const int b = blockIdx.x * 8 + wid;   // one batch per wave
    const int l = threadIdx.x & 63;
    const int* lab = y_true + b * NL;

    int lab_m1 = (l == 0) ? -1 : lab[2 * l - 1];
    int lab0 = lab[2 * l];
    int lab1 = lab[2 * l + 1];
    float sk0 = (lab0 != lab_m1) ? 1.0f : 0.0f;  // skip into state 4l+1
    float sk1 = (lab1 != lab0) ? 1.0f : 0.0f;    // skip into state 4l+3

    // sum_t log eb(t): 16 values per lane, coalesced, then wave-reduce
    float slog = 0.0f;
#pragma unroll
    for (int k = 0; k < NT / 64; k++)
        slog += logf(Bv[b * NT + k * 64 + l]);
    float sred = dpp_wave_sum63(slog);  // lane 63 holds the total

    float p0 = (l == 0) ? 1.0f : 0.0f;  // unit mass "before" state 0
    float p1 = 0.0f, p2 = 0.0f, p3 = 0.0f, pS = 0.0f;
    int ksum = 0;

    uint32 L[CHUNK];

    for (int c = 0; c < NCH; ++c) {
        // ---- load 64 t-rows (this wave's dword column), single-buffered
        const uint32* base = A + ((size_t)b * NT + c * CHUNK) * (NL / 2) + l;
#pragma unroll
        for (int j = 0; j < CHUNK; j++) L[j] = base[(size_t)j * (NL / 2)];
        __builtin_amdgcn_sched_barrier(0);  // fence: loads stay above

        // ---- 64 recursion steps from registers
#pragma unroll
        for (int j = 0; j < CHUNK; j++) {
            float qx = __uint_as_float(L[j] << 16);
            float qy = __uint_as_float(L[j] & 0xFFFF0000u);
            float s3 = dpp_wave_shr1(p3);          // state 4l-1 (old)
            float n0 = p0 + s3;                    // state 4l   (blank)
            float n1 = (p1 + p0 + sk0 * s3) * qx;  // state 4l+1
            float n2 = p2 + p1;                    // state 4l+2 (blank)
            float n3 = (p3 + p2 + sk1 * p1) * qy;  // state 4l+3
            pS = pS + p3;  // lane 63: state 256 <- {256, 255(old)}
            p0 = n0; p1 = n1; p2 = n2; p3 = n3;

            if ((j & 15) == 15) {  // exact power-of-2 rescale every 16 steps
                float m = fmaxf(fmaxf(p0, p1), fmaxf(p2, p3));
                m = fmaxf(m, (l == 63) ? pS : 0.0f);
                float mall = fmaxf(dpp_wave_max(m), 1e-30f);
                int e = (int)(__float_as_uint(mall) >> 23) - 127;
                float sc = __uint_as_float((uint32)(127 - e) << 23);
                p0 *= sc; p1 *= sc; p2 *= sc; p3 *= sc; pS *= sc;
                ksum += e;
            }
        }
        __builtin_amdgcn_sched_barrier(0);  // fence: next loads stay below
    }

    if (l == 63) {
        float tot = p3 + pS;  // alpha_T[255] + alpha_T[256] (hat-space)
        out[b] = -(logf(tot) + (float)ksum * 0.69314718055994531f + sred);
    }
}

// ---------------- fallback scan (no gathered q in ws; legacy eb-form) -----
__global__ __launch_bounds__(64) void ctc_rec0(const float* __restrict__ A,
                                               const float* __restrict__ Bv,
                                               const int* __restrict__ y_true,
                                               float* __restrict__ out) {
    const int b = blockIdx.x;
    const int l = threadIdx.x;
    const int* lab = y_true + b * NL;

    int lab_m1 = (l == 0) ? -1 : lab[2 * l - 1];
    int lab0 = lab[2 * l];
    int lab1 = lab[2 * l + 1];
    float sk0 = (lab0 != lab_m1) ? 1.0f : 0.0f;
    float sk1 = (lab1 != lab0) ? 1.0f : 0.0f;

    float p0 = (l == 0) ? 1.0f : 0.0f;
    float p1 = 0.0f, p2 = 0.0f, p3 = 0.0f, pS = 0.0f;
    int ksum = 0;

    for (int t = 0; t < NT; t++) {
        const float* base = A + ((size_t)b * NT + t) * NC;
        float iv = Bv[b * NT + t];
        float eb = (base[NC - 1] + EPSF) * iv;
        float ex = (base[lab0] + EPSF) * iv;
        float ey = (base[lab1] + EPSF) * iv;
        float s3 = dpp_wave_shr1(p3);
        float n0 = (p0 + s3) * eb;
        float n1 = (p1 + p0 + sk0 * s3) * ex;
        float n2 = (p2 + p1) * eb;
        float n3 = (p3 + p2 + sk1 * p1) * ey;
        pS = (pS + p3) * eb;
        p0 = n0; p1 = n1; p2 = n2; p3 = n3;
        if ((t & 15) == 15) {
            float m = fmaxf(fmaxf(p0, p1), fmaxf(p2, p3));
            m = fmaxf(m, (l == 63) ? pS : 0.0f);
            float mall = fmaxf(dpp_wave_max(m), 1e-30f);
            int e = (int)(__float_as_uint(mall) >> 23) - 127;
            float sc = __uint_as_float((uint32)(127 - e) << 23);
            p0 *= sc; p1 *= sc; p2 *= sc; p3 *= sc; pS *= sc;
            ksum += e;
        }
    }

    if (l == 63) {
        float tot = p3 + pS;
        out[b] = -(logf(tot) +
                   (float)(ksum - 8192) * 0.69314718055994531f);
    }
}

extern "C" void kernel_launch(void* const* d_in, const int* in_sizes, int n_in,
                              void* d_out, int out_size, void* d_ws, size_t ws_size,
                              hipStream_t stream) {
    const int* y_true = (const int*)d_in[0];
    const float* y_pred = (const float*)d_in[1];
    float* out = (float*)d_out;

    const size_t qlab_bytes = (size_t)NB * NT * (NL / 2) * sizeof(uint32);  // 16 MiB
    const size_t eb_bytes = (size_t)NB * NT * sizeof(float);                // 256 KiB

    if (ws_size >= qlab_bytes + eb_bytes) {
        uint32* qlab = (uint32*)d_ws;
        float* eblank = (float*)((char*)d_ws + qlab_bytes);
        ctc_prep<<<NB * NT / 4, 256, 0, stream>>>(y_pred, y_true, qlab, eblank, 1);
        ctc_rec1<<<NB / 8, 512, 0, stream>>>(qlab, eblank, y_true, out);
    } else {
        float* invb = (float*)d_ws;
        ctc_prep<<<NB * NT / 4, 256, 0, stream>>>(y_pred, y_true, nullptr, invb, 0);
        ctc_rec0<<<NB, 64, 0, stream>>>(y_pred, invb, y_true, out);
    }
}

// Round 7
// 56.141 us; speedup vs baseline: 1.5094x; 1.5094x over previous
//
#include <hip/hip_runtime.h>

// CTC batch cost, B=64 T=1024 C=512 (blank=C-1) L=128, S=2L+1=257.
// q-ratio probability-domain forward scan with packed-f32 state pairs:
//   blank states are pure adds, label states multiply by
//   q = (y_lab+eps)/(y_blank+eps);
//   loss = -(log(p255+p256) + ksum*ln2 + sum_t log eb(t)).
// Lane l owns states 4l..4l+3 as pairs X=(p0,p2), Y=(p1,p3) so the
// recursion maps to v_pk_add/v_pk_fma/v_pk_mul_f32 (2 states/instr):
//   nX = X + (s3,p1);  nY = ((X+Y) + SK*(s3,p1)) * Q
// State 256 lives only in lane 63 (pS). Neighbor exchange via DPP
// wave_shr:1 (0x138). Exact power-of-2 rescale every 32 steps.
// CHUNK=32 register double-buffer with sched_barrier fences pinning the
// prefetch block above the compute block. Grid 64 blocks x 64 threads.

#define EPSF 1e-7f
static constexpr int NB = 64;
static constexpr int NT = 1024;
static constexpr int NC = 512;
static constexpr int NL = 128;
static constexpr int CHUNK = 32;
static constexpr int NCH = NT / CHUNK;  // 32

typedef unsigned int uint32;
typedef float v2f __attribute__((ext_vector_type(2)));

__device__ __forceinline__ unsigned short rn_bf16(float x) {
    uint32 b = __float_as_uint(x);
    return (unsigned short)((b + 0x7FFFu + ((b >> 16) & 1u)) >> 16);
}

// ---------------- kernel A: rowsum + q-gather, grid-stride ----------------
__global__ __launch_bounds__(256) void ctc_prep(const float* __restrict__ Y,
                                                const int* __restrict__ y_true,
                                                uint32* __restrict__ qlab,
                                                float* __restrict__ eblank,
                                                int mode) {
    const int lane = threadIdx.x & 63;
    const int wslot = threadIdx.x >> 6;  // 0..3
    const int nw = gridDim.x * 4;

    for (int w = blockIdx.x * 4 + wslot; w < NB * NT; w += nw) {
        int b = w >> 10;
        const float* row = Y + (size_t)w * NC;

        float4 v0 = *reinterpret_cast<const float4*>(row + lane * 4);
        float4 v1 = *reinterpret_cast<const float4*>(row + (NC / 2) + lane * 4);
        float s = ((v0.x + v0.y) + (v0.z + v0.w)) +
                  ((v1.x + v1.y) + (v1.z + v1.w));
#pragma unroll
        for (int d = 1; d < 64; d <<= 1) s += __shfl_xor(s, d);

        if (mode == 1) {
            float rb = row[NC - 1] + EPSF;  // wave-uniform
            float inv = 1.0f / (s + NC * EPSF);
            float rbi = 1.0f / rb;
            int2 lp = *reinterpret_cast<const int2*>(y_true + b * NL + lane * 2);
            float qx = (row[lp.x] + EPSF) * rbi;
            float qy = (row[lp.y] + EPSF) * rbi;
            uint32 pk = (uint32)rn_bf16(qx) | ((uint32)rn_bf16(qy) << 16);
            qlab[(size_t)w * (NL / 2) + lane] = pk;
            if (lane == 0) eblank[w] = rb * inv;  // normalized blank prob
        } else {
            if (lane == 0) eblank[w] = 256.0f / (s + NC * EPSF);
        }
    }
}

// ---------------- DPP helpers ----------------
__device__ __forceinline__ float dpp_wave_shr1(float x) {
    // lane l <- lane l-1, lane 0 <- 0   (DPP_CTRL 0x138 = WAVE_SHR1)
    return __int_as_float(__builtin_amdgcn_update_dpp(
        0, __float_as_int(x), 0x138, 0xF, 0xF, true));
}

__device__ __forceinline__ float dpp_wave_max(float m) {
#define DPPMAX_(ctrl)                                                     \
    m = fmaxf(m, __int_as_float(__builtin_amdgcn_update_dpp(              \
                     0, __float_as_int(m), ctrl, 0xF, 0xF, true)))
    DPPMAX_(0x111); DPPMAX_(0x112); DPPMAX_(0x114); DPPMAX_(0x118);
    DPPMAX_(0x142); DPPMAX_(0x143);
#undef DPPMAX_
    return __int_as_float(
        __builtin_amdgcn_readlane(__float_as_int(m), 63));
}

__device__ __forceinline__ float dpp_wave_sum63(float v) {
#define DPPADD_(ctrl)                                                     \
    v += __int_as_float(__builtin_amdgcn_update_dpp(                      \
        0, __float_as_int(v), ctrl, 0xF, 0xF, true))
    DPPADD_(0x111); DPPADD_(0x112); DPPADD_(0x114); DPPADD_(0x118);
    DPPADD_(0x142); DPPADD_(0x143);
#undef DPPADD_
    return v;
}

// ---------------- kernel B: packed-f32 scan ----------------
__global__ __launch_bounds__(64) void ctc_rec1(const uint32* __restrict__ A,
                                               const float* __restrict__ Bv,
                                               const int* __restrict__ y_true,
                                               float* __restrict__ out) {
    const int b = blockIdx.x;
    const int l = threadIdx.x;
    const int* lab = y_true + b * NL;

    int lab_m1 = (l == 0) ? -1 : lab[2 * l - 1];
    int lab0 = lab[2 * l];
    int lab1 = lab[2 * l + 1];
    v2f SK = {(lab0 != lab_m1) ? 1.0f : 0.0f,
              (lab1 != lab0) ? 1.0f : 0.0f};

    // sum_t log eb(t): 16 values per lane, coalesced, then wave-reduce
    float slog = 0.0f;
#pragma unroll
    for (int k = 0; k < NT / 64; k++)
        slog += logf(Bv[b * NT + k * 64 + l]);
    float sred = dpp_wave_sum63(slog);  // lane 63 holds the total

    v2f X = {(l == 0) ? 1.0f : 0.0f, 0.0f};  // (p0, p2); unit mass pre-state-0
    v2f Y = {0.0f, 0.0f};                    // (p1, p3)
    float pS = 0.0f;
    int ksum = 0;

    uint32 La[CHUNK], Lb[CHUNK];

    auto load = [&](int c, uint32(&L)[CHUNK]) {
        const uint32* base = A + ((size_t)b * NT + c * CHUNK) * (NL / 2) + l;
#pragma unroll
        for (int j = 0; j < CHUNK; j++) L[j] = base[(size_t)j * (NL / 2)];
    };

    auto process = [&](uint32(&L)[CHUNK]) {
#pragma unroll
        for (int j = 0; j < CHUNK; j++) {
            float s3 = dpp_wave_shr1(Y.y);  // state 4l-1 (old)
            v2f Q = {__uint_as_float(L[j] << 16),
                     __uint_as_float(L[j] & 0xFFFF0000u)};
            v2f S = {s3, Y.x};              // (s3, p1)
            v2f T = X + Y;                  // (p0+p1, p2+p3)
            pS += Y.y;                      // lane 63: state 256 += state 255
            v2f nY = (T + SK * S) * Q;      // label states
            X = X + S;                      // blank states
            Y = nY;
        }
        // exact power-of-2 rescale once per 32 steps
        v2f M2 = {fmaxf(X.x, Y.x), fmaxf(X.y, Y.y)};
        float m = fmaxf(M2.x, M2.y);
        m = fmaxf(m, (l == 63) ? pS : 0.0f);
        float mall = fmaxf(dpp_wave_max(m), 1e-30f);
        int e = (int)(__float_as_uint(mall) >> 23) - 127;
        float sc = __uint_as_float((uint32)(127 - e) << 23);
        X = X * sc; Y = Y * sc; pS *= sc;
        ksum += e;
    };

    load(0, La);
    for (int c = 0; c < NCH; c += 2) {
        __builtin_amdgcn_sched_barrier(0);
        if (c + 1 < NCH) load(c + 1, Lb);
        __builtin_amdgcn_sched_barrier(0);
        process(La);
        __builtin_amdgcn_sched_barrier(0);
        if (c + 2 < NCH) load(c + 2, La);
        __builtin_amdgcn_sched_barrier(0);
        process(Lb);
    }

    if (l == 63) {
        float tot = Y.y + pS;  // alpha_T[255] + alpha_T[256] (hat-space)
        out[b] = -(logf(tot) + (float)ksum * 0.69314718055994531f + sred);
    }
}

// ---------------- fallback scan (no staged q in ws; legacy eb-form) -------
__global__ __launch_bounds__(64) void ctc_rec0(const float* __restrict__ A,
                                               const float* __restrict__ Bv,
                                               const int* __restrict__ y_true,
                                               float* __restrict__ out) {
    const int b = blockIdx.x;
    const int l = threadIdx.x;
    const int* lab = y_true + b * NL;

    int lab_m1 = (l == 0) ? -1 : lab[2 * l - 1];
    int lab0 = lab[2 * l];
    int lab1 = lab[2 * l + 1];
    float sk0 = (lab0 != lab_m1) ? 1.0f : 0.0f;
    float sk1 = (lab1 != lab0) ? 1.0f : 0.0f;

    float p0 = (l == 0) ? 1.0f : 0.0f;
    float p1 = 0.0f, p2 = 0.0f, p3 = 0.0f, pS = 0.0f;
    int ksum = 0;

    for (int t = 0; t < NT; t++) {
        const float* base = A + ((size_t)b * NT + t) * NC;
        float iv = Bv[b * NT + t];
        float eb = (base[NC - 1] + EPSF) * iv;
        float ex = (base[lab0] + EPSF) * iv;
        float ey = (base[lab1] + EPSF) * iv;
        float s3 = dpp_wave_shr1(p3);
        float n0 = (p0 + s3) * eb;
        float n1 = (p1 + p0 + sk0 * s3) * ex;
        float n2 = (p2 + p1) * eb;
        float n3 = (p3 + p2 + sk1 * p1) * ey;
        pS = (pS + p3) * eb;
        p0 = n0; p1 = n1; p2 = n2; p3 = n3;
        if ((t & 15) == 15) {
            float m = fmaxf(fmaxf(p0, p1), fmaxf(p2, p3));
            m = fmaxf(m, (l == 63) ? pS : 0.0f);
            float mall = fmaxf(dpp_wave_max(m), 1e-30f);
            int e = (int)(__float_as_uint(mall) >> 23) - 127;
            float sc = __uint_as_float((uint32)(127 - e) << 23);
            p0 *= sc; p1 *= sc; p2 *= sc; p3 *= sc; pS *= sc;
            ksum += e;
        }
    }

    if (l == 63) {
        float tot = p3 + pS;
        out[b] = -(logf(tot) +
                   (float)(ksum - 8192) * 0.69314718055994531f);
    }
}

extern "C" void kernel_launch(void* const* d_in, const int* in_sizes, int n_in,
                              void* d_out, int out_size, void* d_ws, size_t ws_size,
                              hipStream_t stream) {
    const int* y_true = (const int*)d_in[0];
    const float* y_pred = (const float*)d_in[1];
    float* out = (float*)d_out;

    const size_t qlab_bytes = (size_t)NB * NT * (NL / 2) * sizeof(uint32);  // 16 MiB
    const size_t eb_bytes = (size_t)NB * NT * sizeof(float);                // 256 KiB

    if (ws_size >= qlab_bytes + eb_bytes) {
        uint32* qlab = (uint32*)d_ws;
        float* eblank = (float*)((char*)d_ws + qlab_bytes);
        ctc_prep<<<2048, 256, 0, stream>>>(y_pred, y_true, qlab, eblank, 1);
        ctc_rec1<<<NB, 64, 0, stream>>>(qlab, eblank, y_true, out);
    } else {
        float* invb = (float*)d_ws;
        ctc_prep<<<2048, 256, 0, stream>>>(y_pred, y_true, nullptr, invb, 0);
        ctc_rec0<<<NB, 64, 0, stream>>>(y_pred, invb, y_true, out);
    }
}